// Round 3
// baseline (557.029 us; speedup 1.0000x reference)
//
#include <hip/hip_runtime.h>
#include <hip/hip_bf16.h>
#include <stdint.h>

// ---------------------------------------------------------------------------
// BondPoolingLayer: out[e] = MLP(cat(h[src],h[dst])) + MLP(cat(h[dst],h[src]))
// MLP: 256 ->(W1,b1,relu) 128 ->(W2,b2,relu) 128 ->(W3,b3) 2
//
// P[n,0:128] = h[n] @ W1_top ; P[n,128:256] = h[n] @ W1_bot + b1   (bf16)
//   fwd layer1 preact = P[s,0:128] + P[d,128:256]
//   rev layer1 preact = P[d,0:128] + P[s,128:256]
//
// R8: persistent blocks + ENGINEERED live-set < 128 + hard cap 128.
//  - R6 post-mortem: cap 128 with irreducible live-set 128 -> spill storm.
//  - R7 post-mortem: cap 256 -> compiler pipelined regs 56->128 arch (+64
//    AGPR = 192) -> occupancy fell to 1 block/CU AND partial spills stayed.
//    Lesson: live-set must be designed below the cap, then capped.
//  - node_proj: two acc[8] passes (feat 0..127, then 128..255 +b1-from-LDS).
//    Peak live ~100 regs. __launch_bounds__(512,4) => 2 blocks/CU guaranteed.
//  - edge_mlp: fwd/rev as sequential acc[8] passes folded into p0/p1.
//    Peak live ~105 regs. Same cap. W2s ds_reads double (LDS has headroom).
// ---------------------------------------------------------------------------

typedef __attribute__((ext_vector_type(8))) short bf16x8;
typedef __attribute__((ext_vector_type(4))) float f32x4;

__device__ __forceinline__ float bf2f(unsigned u16) {
    union { unsigned u; float f; } v; v.u = u16 << 16;
    return v.f;
}
__device__ __forceinline__ unsigned short f2bf(float f) {
    union { float f; unsigned u; } v; v.f = f;
    unsigned u = v.u;
    unsigned r = u + 0x7FFFu + ((u >> 16) & 1u);   // RNE
    return (unsigned short)(r >> 16);
}

// LDS swizzle: tiles are [rows][128 bf16], chunk = 8 bf16 (16B), 16 chunks/row.
__device__ __forceinline__ int swz(int f, int c) {
    return f * 128 + ((c ^ (f & 7)) << 3);
}

// 8 consecutive fp32 -> bf16x8 fragment (packed RNE cvt)
__device__ __forceinline__ bf16x8 cvt8(const float* p) {
    float4 x = *(const float4*)p;
    float4 y = *(const float4*)(p + 4);
    union { bf16x8 v; __hip_bfloat162 h[4]; } R;
    R.h[0] = __float22bfloat162_rn(float2{x.x, x.y});
    R.h[1] = __float22bfloat162_rn(float2{x.z, x.w});
    R.h[2] = __float22bfloat162_rn(float2{y.x, y.y});
    R.h[3] = __float22bfloat162_rn(float2{y.z, y.w});
    return R.v;
}

// elementwise relu(a+b) over 8 bf16 pairs (fp32 math), repacked to bf16x8
__device__ __forceinline__ bf16x8 addrelu8(uint4 a, uint4 b) {
    union { uint4 v; unsigned u[4]; } A, B;
    A.v = a; B.v = b;
    union { bf16x8 v; __hip_bfloat162 h[4]; } R;
#pragma unroll
    for (int i = 0; i < 4; ++i) {
        float a0 = bf2f(A.u[i] & 0xFFFFu), a1 = bf2f(A.u[i] >> 16);
        float b0 = bf2f(B.u[i] & 0xFFFFu), b1 = bf2f(B.u[i] >> 16);
        R.h[i] = __float22bfloat162_rn(float2{fmaxf(a0 + b0, 0.f),
                                              fmaxf(a1 + b1, 0.f)});
    }
    return R.v;
}

#define MFMA(a, b, c) __builtin_amdgcn_mfma_f32_16x16x32_bf16((a), (b), (c), 0, 0, 0)

// ---------------------------------------------------------------------------
// Kernel 0: weight prep (bf16 transposes, plain row-major).
// ---------------------------------------------------------------------------
__global__ void prep_weights(const float* __restrict__ W1,
                             const float* __restrict__ W2,
                             unsigned short* __restrict__ W1t,
                             unsigned short* __restrict__ W2t) {
    int idx = blockIdx.x * 256 + threadIdx.x;
    if (idx < 256 * 128) {
        int j = idx >> 7, k = idx & 127;
        float v = (j < 128) ? W1[k * 128 + j] : W1[(k + 128) * 128 + (j - 128)];
        W1t[idx] = f2bf(v);
    } else {
        int i2 = idx - 256 * 128;
        if (i2 < 128 * 128) {
            int n = i2 >> 7, k = i2 & 127;
            W2t[i2] = f2bf(W2[k * 128 + n]);
        }
    }
}

// ---------------------------------------------------------------------------
// Kernel A: node projection. Persistent blocks, two acc[8] passes per tile.
// Wave = 16 nodes x 256 features. Cap 128 regs => 2 blocks/CU guaranteed;
// designed live-set ~100 so the cap does NOT force spills (R6 lesson).
// ---------------------------------------------------------------------------
__global__ __launch_bounds__(512, 4) void node_proj(
    const float* __restrict__ h, const unsigned short* __restrict__ W1t,
    const float* __restrict__ b1, unsigned short* __restrict__ P, int nodes) {
    __shared__ unsigned short W1s[256 * 128];
    __shared__ float cb1[128];

    int t = threadIdx.x;
    int lane = t & 63;
    int wv = t >> 6;
    int ml = lane & 15, quad = lane >> 4;

    // stage W1s once: thread t -> row t>>1, 8 chunks (swizzled)
    {
        int r = t >> 1, half = t & 1;
        const uint4* srcp = (const uint4*)(W1t + (size_t)r * 128 + half * 64);
#pragma unroll
        for (int i = 0; i < 8; ++i)
            *(uint4*)(W1s + swz(r, half * 8 + i)) = srcp[i];
    }
    if (t < 32) ((float4*)cb1)[t] = ((const float4*)b1)[t];
    __syncthreads();   // LDS ready; no barriers from here on

    int ntiles = (nodes + 127) >> 7;
    for (int tile = blockIdx.x; tile < ntiles; tile += gridDim.x) {
        int node = tile * 128 + wv * 16 + ml;
        int nodeL = (node < nodes) ? node : (nodes - 1);
        const float* hrow = h + (size_t)nodeL * 128;

        bf16x8 bfrag[4];
#pragma unroll
        for (int kk = 0; kk < 4; ++kk)
            bfrag[kk] = cvt8(hrow + kk * 32 + quad * 8);

        unsigned short* prow = P + (size_t)node * 256;
        bool ok = (node < nodes);

        // ---- pass A: features 0..127 (no bias) ----
        {
            f32x4 acc[8] = {};
#pragma unroll
            for (int kk = 0; kk < 4; ++kk) {
#pragma unroll
                for (int ct = 0; ct < 8; ++ct) {
                    bf16x8 afrag = *(const bf16x8*)(W1s + swz(ct * 16 + ml, kk * 4 + quad));
                    acc[ct] = MFMA(afrag, bfrag[kk], acc[ct]);
                }
            }
            if (ok) {
#pragma unroll
                for (int ct = 0; ct < 8; ++ct) {
                    int fb = ct * 16 + quad * 4;
                    union { uint2 u; __hip_bfloat162 h2[2]; } o;
                    o.h2[0] = __float22bfloat162_rn(float2{acc[ct][0], acc[ct][1]});
                    o.h2[1] = __float22bfloat162_rn(float2{acc[ct][2], acc[ct][3]});
                    *(uint2*)(prow + fb) = o.u;
                }
            }
        }

        // ---- pass B: features 128..255 (+b1) ----
        {
            f32x4 acc[8] = {};
#pragma unroll
            for (int kk = 0; kk < 4; ++kk) {
#pragma unroll
                for (int ct = 0; ct < 8; ++ct) {
                    bf16x8 afrag = *(const bf16x8*)(W1s + swz(128 + ct * 16 + ml, kk * 4 + quad));
                    acc[ct] = MFMA(afrag, bfrag[kk], acc[ct]);
                }
            }
            if (ok) {
#pragma unroll
                for (int ct = 0; ct < 8; ++ct) {
                    int fb = ct * 16 + quad * 4;
                    float4 bv = *(const float4*)(cb1 + fb);
                    union { uint2 u; __hip_bfloat162 h2[2]; } o;
                    o.h2[0] = __float22bfloat162_rn(float2{acc[ct][0] + bv.x, acc[ct][1] + bv.y});
                    o.h2[1] = __float22bfloat162_rn(float2{acc[ct][2] + bv.z, acc[ct][3] + bv.w});
                    *(uint2*)(prow + 128 + fb) = o.u;
                }
            }
        }
    }
}

// ---------------------------------------------------------------------------
// Kernel B: per-edge MLP. Persistent blocks; fwd/rev as sequential acc[8]
// passes folded straight into p0/p1. Wave = 16 edges. Cap 128 => 2 blocks/CU.
// ---------------------------------------------------------------------------
__global__ __launch_bounds__(512, 4) void edge_mlp(
    const unsigned short* __restrict__ P, const int* __restrict__ src,
    const int* __restrict__ dst, const unsigned short* __restrict__ W2t,
    const float* __restrict__ b2, const float* __restrict__ W3,
    const float* __restrict__ b3, float* __restrict__ out, int E) {
    __shared__ unsigned short W2s[128 * 128];
    __shared__ float2 cW3[128];
    __shared__ float  cb2[128];

    int t = threadIdx.x;
    int lane = t & 63;
    int wv = t >> 6;
    int ml = lane & 15, quad = lane >> 4;

    // stage W2s once: thread t -> row t>>2, 4 chunks (swizzled)
    {
        int f = t >> 2, q4 = t & 3;
        const uint4* s = (const uint4*)(W2t + (size_t)f * 128 + q4 * 32);
#pragma unroll
        for (int i = 0; i < 4; ++i)
            *(uint4*)(W2s + swz(f, q4 * 4 + i)) = s[i];
    }
    if (t < 128) {
        cW3[t] = float2{W3[t * 2 + 0], W3[t * 2 + 1]};
        cb2[t] = b2[t];
    }
    __syncthreads();   // LDS ready; no barriers from here on

    int etiles = (E + 127) >> 7;

    // prefetch first tile's indices
    int tile = blockIdx.x;
    int e0 = tile * 128 + wv * 16 + ml;
    int ec0 = (e0 < E) ? e0 : (E - 1);
    int si = src[ec0], di = dst[ec0];

    for (; tile < etiles; tile += gridDim.x) {
        // prefetch next tile's indices
        int tn = tile + gridDim.x;
        int en = tn * 128 + wv * 16 + ml;
        int ecn = (tn < etiles) ? ((en < E) ? en : (E - 1)) : 0;
        int sin = src[ecn], din = dst[ecn];

        const unsigned short* Ps = P + (size_t)si * 256;
        const unsigned short* Pd = P + (size_t)di * 256;

        // gather + convert: gathers retire per-kk; afw/arv (32 regs) carry
        bf16x8 afw[4], arv[4];
#pragma unroll
        for (int kk = 0; kk < 4; ++kk) {
            int ko = kk * 32 + quad * 8;
            uint4 slo = *(const uint4*)(Ps + ko);
            uint4 shi = *(const uint4*)(Ps + 128 + ko);
            uint4 dlo = *(const uint4*)(Pd + ko);
            uint4 dhi = *(const uint4*)(Pd + 128 + ko);
            afw[kk] = addrelu8(slo, dhi);   // fwd: relu(P[s,k]+P[d,128+k])
            arv[kk] = addrelu8(dlo, shi);   // rev: relu(P[d,k]+P[s,128+k])
        }

        float p0[4] = {0.f, 0.f, 0.f, 0.f};
        float p1[4] = {0.f, 0.f, 0.f, 0.f};

        // ---- pass fwd ----
        {
            f32x4 acc[8] = {};
#pragma unroll
            for (int kk = 0; kk < 4; ++kk) {
#pragma unroll
                for (int ct = 0; ct < 8; ++ct) {
                    bf16x8 bfrag = *(const bf16x8*)(W2s + swz(ct * 16 + ml, kk * 4 + quad));
                    acc[ct] = MFMA(afw[kk], bfrag, acc[ct]);
                }
            }
#pragma unroll
            for (int ct = 0; ct < 8; ++ct) {
                int c = ct * 16 + ml;
                float2 w3 = cW3[c];
                float bc = cb2[c];
#pragma unroll
                for (int reg = 0; reg < 4; ++reg) {
                    float h2 = fmaxf(acc[ct][reg] + bc, 0.f);
                    p0[reg] += h2 * w3.x;
                    p1[reg] += h2 * w3.y;
                }
            }
        }
        // ---- pass rev ----
        {
            f32x4 acc[8] = {};
#pragma unroll
            for (int kk = 0; kk < 4; ++kk) {
#pragma unroll
                for (int ct = 0; ct < 8; ++ct) {
                    bf16x8 bfrag = *(const bf16x8*)(W2s + swz(ct * 16 + ml, kk * 4 + quad));
                    acc[ct] = MFMA(arv[kk], bfrag, acc[ct]);
                }
            }
#pragma unroll
            for (int ct = 0; ct < 8; ++ct) {
                int c = ct * 16 + ml;
                float2 w3 = cW3[c];
                float bc = cb2[c];
#pragma unroll
                for (int reg = 0; reg < 4; ++reg) {
                    float h2 = fmaxf(acc[ct][reg] + bc, 0.f);
                    p0[reg] += h2 * w3.x;
                    p1[reg] += h2 * w3.y;
                }
            }
        }

        // butterfly over the 16 feature lanes
#pragma unroll
        for (int m = 1; m < 16; m <<= 1) {
#pragma unroll
            for (int reg = 0; reg < 4; ++reg) {
                p0[reg] += __shfl_xor(p0[reg], m);
                p1[reg] += __shfl_xor(p1[reg], m);
            }
        }

        // lane ml==0 writes component 0, ml==1 writes component 1
        if (ml < 2) {
            float bb = 2.f * b3[ml];
#pragma unroll
            for (int reg = 0; reg < 4; ++reg) {
                int ee = tile * 128 + wv * 16 + quad * 4 + reg;
                if (ee < E) {
                    float v = (ml == 0) ? p0[reg] : p1[reg];
                    out[(size_t)ee * 2 + ml] = v + bb;
                }
            }
        }

        si = sin; di = din;
    }
}

// ---------------------------------------------------------------------------
extern "C" void kernel_launch(void* const* d_in, const int* in_sizes, int n_in,
                              void* d_out, int out_size, void* d_ws, size_t ws_size,
                              hipStream_t stream) {
    (void)n_in; (void)out_size; (void)ws_size;
    const float* h  = (const float*)d_in[0];
    const int*   sr = (const int*)d_in[1];
    const int*   ds = (const int*)d_in[2];
    const float* W1 = (const float*)d_in[3];
    const float* b1 = (const float*)d_in[4];
    const float* W2 = (const float*)d_in[5];
    const float* b2 = (const float*)d_in[6];
    const float* W3 = (const float*)d_in[7];
    const float* b3 = (const float*)d_in[8];
    float* out = (float*)d_out;

    int nodes = in_sizes[0] / 128;
    int E = in_sizes[1];

    unsigned short* W1t = (unsigned short*)d_ws;          // 256*128
    unsigned short* W2t = W1t + 256 * 128;                // 128*128
    unsigned short* P   = W2t + 128 * 128;                // nodes*256

    prep_weights<<<(256 * 128 + 128 * 128 + 255) / 256, 256, 0, stream>>>(W1, W2, W1t, W2t);

    // persistent grids: 2 blocks/CU x 256 CU = 512
    int ntiles = (nodes + 127) / 128;
    int ngrid = ntiles < 512 ? ntiles : 512;
    node_proj<<<ngrid, 512, 0, stream>>>(h, W1t, b1, P, nodes);

    int etiles = (E + 127) / 128;
    int egrid = etiles < 512 ? etiles : 512;
    edge_mlp<<<egrid, 512, 0, stream>>>(P, sr, ds, W2t, b2, W3, b3, out, E);
}

// Round 4
// 229.932 us; speedup vs baseline: 2.4226x; 2.4226x over previous
//
#include <hip/hip_runtime.h>
#include <hip/hip_bf16.h>
#include <stdint.h>

// ---------------------------------------------------------------------------
// BondPoolingLayer: out[e] = MLP(cat(h[src],h[dst])) + MLP(cat(h[dst],h[src]))
// MLP: 256 ->(W1,b1,relu) 128 ->(W2,b2,relu) 128 ->(W3,b3) 2
//
// P[n,0:128] = h[n] @ W1_top ; P[n,128:256] = h[n] @ W1_bot + b1   (bf16)
//   fwd layer1 preact = P[s,0:128] + P[d,128:256]
//   rev layer1 preact = P[d,0:128] + P[s,128:256]
//
// R9 = R5 skeleton (per-tile blocks, proven clean: 56+64 regs, 0 spill)
//      + coalesced LDS-bounce epilogue in node_proj.
//  - R6/R7/R8 post-mortem: persistent tile-loops are toxic for this
//    toolchain — cap 128 => spill storm (even with ~96-reg live-set),
//    cap 256 => reg balloon to 192 => 1 block/CU. Reverted for good.
//  - R5 residual: node_proj moves ideal bytes at only 1.9 TB/s, all pipes
//    idle. Suspect: epilogue uint2 stores = 16x 32B segments per wave instr.
//  - Fix: after MFMA, W1s is dead -> barrier -> stage output in the same
//    64KB LDS (16B-chunk XOR swizzle) -> barrier -> wave-linear readout +
//    global_store_dwordx4 (1KB/instr, block's P region is 64KB contiguous).
// ---------------------------------------------------------------------------

typedef __attribute__((ext_vector_type(8))) short bf16x8;
typedef __attribute__((ext_vector_type(4))) float f32x4;

__device__ __forceinline__ float bf2f(unsigned u16) {
    union { unsigned u; float f; } v; v.u = u16 << 16;
    return v.f;
}
__device__ __forceinline__ unsigned short f2bf(float f) {
    union { float f; unsigned u; } v; v.f = f;
    unsigned u = v.u;
    unsigned r = u + 0x7FFFu + ((u >> 16) & 1u);   // RNE
    return (unsigned short)(r >> 16);
}

// LDS swizzle: tiles are [rows][128 bf16], chunk = 8 bf16 (16B), 16 chunks/row.
__device__ __forceinline__ int swz(int f, int c) {
    return f * 128 + ((c ^ (f & 7)) << 3);
}

// 8 consecutive fp32 -> bf16x8 fragment (packed RNE cvt)
__device__ __forceinline__ bf16x8 cvt8(const float* p) {
    float4 x = *(const float4*)p;
    float4 y = *(const float4*)(p + 4);
    union { bf16x8 v; __hip_bfloat162 h[4]; } R;
    R.h[0] = __float22bfloat162_rn(float2{x.x, x.y});
    R.h[1] = __float22bfloat162_rn(float2{x.z, x.w});
    R.h[2] = __float22bfloat162_rn(float2{y.x, y.y});
    R.h[3] = __float22bfloat162_rn(float2{y.z, y.w});
    return R.v;
}

// elementwise relu(a+b) over 8 bf16 pairs (fp32 math), repacked to bf16x8
__device__ __forceinline__ bf16x8 addrelu8(uint4 a, uint4 b) {
    union { uint4 v; unsigned u[4]; } A, B;
    A.v = a; B.v = b;
    union { bf16x8 v; __hip_bfloat162 h[4]; } R;
#pragma unroll
    for (int i = 0; i < 4; ++i) {
        float a0 = bf2f(A.u[i] & 0xFFFFu), a1 = bf2f(A.u[i] >> 16);
        float b0 = bf2f(B.u[i] & 0xFFFFu), b1 = bf2f(B.u[i] >> 16);
        R.h[i] = __float22bfloat162_rn(float2{fmaxf(a0 + b0, 0.f),
                                              fmaxf(a1 + b1, 0.f)});
    }
    return R.v;
}

#define MFMA(a, b, c) __builtin_amdgcn_mfma_f32_16x16x32_bf16((a), (b), (c), 0, 0, 0)

// ---------------------------------------------------------------------------
// Kernel 0: weight prep (bf16 transposes, plain row-major).
// ---------------------------------------------------------------------------
__global__ void prep_weights(const float* __restrict__ W1,
                             const float* __restrict__ W2,
                             unsigned short* __restrict__ W1t,
                             unsigned short* __restrict__ W2t) {
    int idx = blockIdx.x * 256 + threadIdx.x;
    if (idx < 256 * 128) {
        int j = idx >> 7, k = idx & 127;
        float v = (j < 128) ? W1[k * 128 + j] : W1[(k + 128) * 128 + (j - 128)];
        W1t[idx] = f2bf(v);
    } else {
        int i2 = idx - 256 * 128;
        if (i2 < 128 * 128) {
            int n = i2 >> 7, k = i2 & 127;
            W2t[i2] = f2bf(W2[k * 128 + n]);
        }
    }
}

// ---------------------------------------------------------------------------
// Kernel A: node projection. Per-tile blocks (R5 structure). 512 thr = 8
// waves = 128 nodes; wave = 16 nodes x 256 features (acc[16] = 64 AGPR).
// New: epilogue bounces through the (now dead) W1s LDS so global stores are
// wave-linear dwordx4 (1KB/instr) instead of 16x 32B scattered segments.
// ---------------------------------------------------------------------------
__global__ __launch_bounds__(512, 2) void node_proj(
    const float* __restrict__ h, const unsigned short* __restrict__ W1t,
    const float* __restrict__ b1, unsigned short* __restrict__ P, int nodes) {
    __shared__ unsigned short W1s[256 * 128];   // reused as output staging

    int t = threadIdx.x;
    int lane = t & 63;
    int wv = t >> 6;
    int ml = lane & 15, quad = lane >> 4;

    // stage W1s: thread t -> row t>>1, 8 chunks (swizzled)
    {
        int r = t >> 1, half = t & 1;
        const uint4* srcp = (const uint4*)(W1t + (size_t)r * 128 + half * 64);
#pragma unroll
        for (int i = 0; i < 8; ++i)
            *(uint4*)(W1s + swz(r, half * 8 + i)) = srcp[i];
    }

    // prefetch + convert h for this wave's 16 nodes (B-operand: n = ml)
    int node = blockIdx.x * 128 + wv * 16 + ml;
    int nodeL = (node < nodes) ? node : (nodes - 1);
    const float* hrow = h + (size_t)nodeL * 128;
    bf16x8 bfrag[4];
#pragma unroll
    for (int kk = 0; kk < 4; ++kk)
        bfrag[kk] = cvt8(hrow + kk * 32 + quad * 8);

    __syncthreads();   // W1s ready

    f32x4 acc[16] = {};
#pragma unroll
    for (int kk = 0; kk < 4; ++kk) {
#pragma unroll
        for (int ct = 0; ct < 16; ++ct) {
            bf16x8 afrag = *(const bf16x8*)(W1s + swz(ct * 16 + ml, kk * 4 + quad));
            acc[ct] = MFMA(afrag, bfrag[kk], acc[ct]);
        }
    }

    __syncthreads();   // all waves done READING W1s; safe to overwrite

    // write acc -> LDS staging. Row = wv*16+ml (512B), 16B chunks XOR-swizzled
    // by row so the linear readout below is bank-spread.
    {
        unsigned short* orow = W1s + (wv * 16 + ml) * 256;
#pragma unroll
        for (int ct = 0; ct < 16; ++ct) {
            int fbase = ct * 16 + quad * 4;
            float v0 = acc[ct][0], v1 = acc[ct][1];
            float v2 = acc[ct][2], v3 = acc[ct][3];
            if (fbase >= 128) {
                float4 bv = *(const float4*)(b1 + (fbase - 128));
                v0 += bv.x; v1 += bv.y; v2 += bv.z; v3 += bv.w;
            }
            union { uint2 u; __hip_bfloat162 h2[2]; } o;
            o.h2[0] = __float22bfloat162_rn(float2{v0, v1});
            o.h2[1] = __float22bfloat162_rn(float2{v2, v3});
            int c = ct * 2 + (quad >> 1);          // 16B chunk index in row
            *(uint2*)(orow + ((c ^ ml) << 3) + ((quad & 1) << 2)) = o.u;
        }
    }
    __syncthreads();   // staging ready

    // coalesced readout + store: per thread 8 x dwordx4; per wave-instr 1KB
    // linear. Block's P region (128 rows x 512B) is contiguous.
    {
        size_t pbase = (size_t)blockIdx.x * (128 * 256);
        int nbase = blockIdx.x * 128;
#pragma unroll
        for (int j = 0; j < 8; ++j) {
            int off = wv * 8192 + j * 1024 + lane * 16;   // byte offset in tile
            int row = off >> 9;
            int c = (off & 511) >> 4;
            uint4 v = *(const uint4*)(W1s + row * 256 + ((c ^ (row & 15)) << 3));
            if (nbase + row < nodes)
                *(uint4*)(P + pbase + (off >> 1)) = v;
        }
    }
}

// ---------------------------------------------------------------------------
// Kernel B: per-edge MLP (byte-identical to R5). Block = 512 thr = 8 waves =
// 128 edges. Wave = 16 edges x {fwd,rev}. W2s 32KB staged once per block.
// ---------------------------------------------------------------------------
__global__ __launch_bounds__(512, 2) void edge_mlp(
    const unsigned short* __restrict__ P, const int* __restrict__ src,
    const int* __restrict__ dst, const unsigned short* __restrict__ W2t,
    const float* __restrict__ b2, const float* __restrict__ W3,
    const float* __restrict__ b3, float* __restrict__ out, int E) {
    __shared__ unsigned short W2s[128 * 128];

    int t = threadIdx.x;
    int lane = t & 63;
    int wv = t >> 6;
    int ml = lane & 15, quad = lane >> 4;

    // stage W2s: thread t -> row t>>2, 4 chunks (swizzled)
    {
        int f = t >> 2, q4 = t & 3;
        const uint4* s = (const uint4*)(W2t + (size_t)f * 128 + q4 * 32);
#pragma unroll
        for (int i = 0; i < 4; ++i)
            *(uint4*)(W2s + swz(f, q4 * 4 + i)) = s[i];
    }

    // prefetch all P gathers for this lane's edge
    int e = blockIdx.x * 128 + wv * 16 + ml;
    int ec = (e < E) ? e : (E - 1);
    int si = src[ec], di = dst[ec];
    const unsigned short* Ps = P + (size_t)si * 256;
    const unsigned short* Pd = P + (size_t)di * 256;

    uint4 g[4][4];   // [kk][s_lo, s_hi, d_lo, d_hi]
#pragma unroll
    for (int kk = 0; kk < 4; ++kk) {
        int ko = kk * 32 + quad * 8;
        g[kk][0] = *(const uint4*)(Ps + ko);
        g[kk][1] = *(const uint4*)(Ps + 128 + ko);
        g[kk][2] = *(const uint4*)(Pd + ko);
        g[kk][3] = *(const uint4*)(Pd + 128 + ko);
    }

    __syncthreads();   // W2s ready

    f32x4 acc[2][8] = {};
#pragma unroll
    for (int kk = 0; kk < 4; ++kk) {
        bf16x8 afw = addrelu8(g[kk][0], g[kk][3]);   // fwd: relu(P[s,k]+P[d,128+k])
        bf16x8 arv = addrelu8(g[kk][2], g[kk][1]);   // rev: relu(P[d,k]+P[s,128+k])
#pragma unroll
        for (int ct = 0; ct < 8; ++ct) {
            bf16x8 bfrag = *(const bf16x8*)(W2s + swz(ct * 16 + ml, kk * 4 + quad));
            acc[0][ct] = MFMA(afw, bfrag, acc[0][ct]);
            acc[1][ct] = MFMA(arv, bfrag, acc[1][ct]);
        }
    }

    // epilogue: +b2, relu, dot W3 columns, butterfly over 16 feature lanes
    float w30[8], w31[8], b2v[8];
#pragma unroll
    for (int ct = 0; ct < 8; ++ct) {
        int c = ct * 16 + ml;
        w30[ct] = W3[c * 2 + 0];
        w31[ct] = W3[c * 2 + 1];
        b2v[ct] = b2[c];
    }
    float p0[2][4], p1[2][4];
#pragma unroll
    for (int rt = 0; rt < 2; ++rt)
#pragma unroll
        for (int reg = 0; reg < 4; ++reg) { p0[rt][reg] = 0.f; p1[rt][reg] = 0.f; }
#pragma unroll
    for (int rt = 0; rt < 2; ++rt)
#pragma unroll
        for (int ct = 0; ct < 8; ++ct)
#pragma unroll
            for (int reg = 0; reg < 4; ++reg) {
                float h2 = fmaxf(acc[rt][ct][reg] + b2v[ct], 0.f);
                p0[rt][reg] += h2 * w30[ct];
                p1[rt][reg] += h2 * w31[ct];
            }
#pragma unroll
    for (int m = 1; m < 16; m <<= 1) {
#pragma unroll
        for (int rt = 0; rt < 2; ++rt)
#pragma unroll
            for (int reg = 0; reg < 4; ++reg) {
                p0[rt][reg] += __shfl_xor(p0[rt][reg], m);
                p1[rt][reg] += __shfl_xor(p1[rt][reg], m);
            }
    }

    // lane ml==0 writes component 0, ml==1 writes component 1
    if (ml < 2) {
        float bb = 2.f * b3[ml];
#pragma unroll
        for (int reg = 0; reg < 4; ++reg) {
            int ee = blockIdx.x * 128 + wv * 16 + quad * 4 + reg;
            if (ee < E) {
                float v = (ml == 0) ? (p0[0][reg] + p0[1][reg])
                                    : (p1[0][reg] + p1[1][reg]);
                out[(size_t)ee * 2 + ml] = v + bb;
            }
        }
    }
}

// ---------------------------------------------------------------------------
extern "C" void kernel_launch(void* const* d_in, const int* in_sizes, int n_in,
                              void* d_out, int out_size, void* d_ws, size_t ws_size,
                              hipStream_t stream) {
    (void)n_in; (void)out_size; (void)ws_size;
    const float* h  = (const float*)d_in[0];
    const int*   sr = (const int*)d_in[1];
    const int*   ds = (const int*)d_in[2];
    const float* W1 = (const float*)d_in[3];
    const float* b1 = (const float*)d_in[4];
    const float* W2 = (const float*)d_in[5];
    const float* b2 = (const float*)d_in[6];
    const float* W3 = (const float*)d_in[7];
    const float* b3 = (const float*)d_in[8];
    float* out = (float*)d_out;

    int nodes = in_sizes[0] / 128;
    int E = in_sizes[1];

    unsigned short* W1t = (unsigned short*)d_ws;          // 256*128
    unsigned short* W2t = W1t + 256 * 128;                // 128*128
    unsigned short* P   = W2t + 128 * 128;                // nodes*256

    prep_weights<<<(256 * 128 + 128 * 128 + 255) / 256, 256, 0, stream>>>(W1, W2, W1t, W2t);

    int ntiles = (nodes + 127) / 128;
    node_proj<<<ntiles, 512, 0, stream>>>(h, W1t, b1, P, nodes);

    int etiles = (E + 127) / 128;
    edge_mlp<<<etiles, 512, 0, stream>>>(P, sr, ds, W2t, b2, W3, b3, out, E);
}